// Round 9
// baseline (900.109 us; speedup 1.0000x reference)
//
#include <hip/hip_runtime.h>
#include <hip/hip_cooperative_groups.h>
#include <stdint.h>

namespace cg = cooperative_groups;

// B = 1048576 rows, HID = 64. Residual MLP with training-mode BatchNorm.
// Round 9: cooperative persistent kernel, grid-size-agnostic (grid-stride
// tiles), __launch_bounds__(256,2) so 2 blocks/CU always fit; grid clamped
// via occupancy query; runtime FALLBACK to the proven R7 multi-kernel path
// if cooperative launch is rejected.
// MFMA 16x16x32 bf16 layouts (verified):
//   A: row = lane&15, k = (lane>>4)*8 + j ; B: col = lane&15, same k
//   C/D: col = lane&15, row = (lane>>4)*4 + reg
// Identity trick: D = A * I_p picks cols 16p..16p+15 of A into C-layout.

#define NROWS 1048576
#define NTILES 8192
#define EPS 1e-5f
#define INV_B 9.5367431640625e-07f  // 1/2^20 exact
#define LOG2E2 2.885390081777927f   // 2*log2(e)

typedef __attribute__((ext_vector_type(8))) short bfrag;   // 8 bf16
typedef __attribute__((ext_vector_type(4))) float facc;    // MFMA C/D
typedef __attribute__((ext_vector_type(4))) float f4v;

__device__ __forceinline__ float bf2f(short s) {
  union { unsigned u; float f; } v;
  v.u = ((unsigned)(unsigned short)s) << 16;
  return v.f;
}
__device__ __forceinline__ short f2bf(float f) {
  union { float f; unsigned u; } v;
  v.f = f;
  unsigned r = v.u + 0x7FFFu + ((v.u >> 16) & 1u);  // RNE
  return (short)(r >> 16);
}
__device__ __forceinline__ float tanh_fast(float x) {
  float e = __builtin_amdgcn_exp2f(x * LOG2E2);
  return 1.f - 2.f * __builtin_amdgcn_rcpf(e + 1.f);
}
__device__ __forceinline__ bfrag make_ident(int l15, int q, int p) {
  bfrag r;
  const short one = (short)0x3F80;
#pragma unroll
  for (int j = 0; j < 8; ++j) r[j] = (q * 8 + j == l15 + 16 * p) ? one : 0;
  return r;
}

// ===================== cooperative persistent kernel ======================

__device__ __forceinline__ void grid_reduce128(float* __restrict__ P,
                                               float* __restrict__ P2,
                                               float* S_lds, float* red_l,
                                               int bid, int tid, int nblk,
                                               cg::grid_group& grid) {
  grid.sync();
  if (bid < 128 && tid < 128) {
    float s = 0.f;
    for (int r = bid; r < nblk; r += 128) s += P[(size_t)r * 128 + tid];
    P2[bid * 128 + tid] = s;
  }
  grid.sync();
  {
    int col = tid & 127, g = tid >> 7;
    float s = 0.f;
    for (int r = g * 64; r < g * 64 + 64; ++r) s += P2[r * 128 + col];
    red_l[tid] = s;
    __syncthreads();
    if (tid < 128) S_lds[tid] = red_l[tid] + red_l[128 + tid];
    __syncthreads();
  }
}

__global__ __launch_bounds__(256, 2) void k_net(
    const float* __restrict__ x, const float* __restrict__ bn0g,
    const float* __restrict__ bn0b, const float* __restrict__ W0,
    const float* __restrict__ b0, const float* __restrict__ gamma0,
    const float* __restrict__ beta0, const float* __restrict__ Wh,
    const float* __restrict__ bh, const float* __restrict__ gh,
    const float* __restrict__ beh, const float* __restrict__ Wout,
    const float* __restrict__ bout, short* __restrict__ WT,
    float* __restrict__ P, float* __restrict__ P2, short* __restrict__ Y,
    float* __restrict__ out) {
  cg::grid_group grid = cg::this_grid();

  __shared__ __align__(16) short ly[128 * 72];      // 18 KB
  __shared__ __align__(16) float lds_x[128 * 4];    // 2 KB
  __shared__ float lds_st[4][128];                  // 2 KB
  __shared__ float S_lds[128];
  __shared__ float red_l[256];

  const int tid = threadIdx.x;
  const int lane = tid & 63;
  const int wave = tid >> 6;
  const int l15 = lane & 15;
  const int q = lane >> 4;
  const int wr = wave * 32;
  const int bid = blockIdx.x;
  const int nblk = (int)gridDim.x;

  //====== phase A: WT prep + x stats (grid-stride chunks of 1024 rows) =====
  for (int i = bid * 256 + tid; i < 16384; i += nblk * 256) {
    int l = i >> 12, rem = i & 4095, k = rem >> 6, c = rem & 63;
    WT[l * 4096 + c * 64 + k] = f2bf(Wh[l * 4096 + k * 64 + c]);
  }
  {
    float s[4] = {0.f, 0.f, 0.f, 0.f}, qq[4] = {0.f, 0.f, 0.f, 0.f};
    for (int c = bid; c < 1024; c += nblk) {
      size_t base = (size_t)c * 1024 + tid;
#pragma unroll
      for (int it = 0; it < 4; ++it) {
        f4v v = *(const f4v*)(x + (base + (size_t)it * 256) * 4);
#pragma unroll
        for (int k = 0; k < 4; ++k) {
          s[k] += v[k];
          qq[k] = fmaf(v[k], v[k], qq[k]);
        }
      }
    }
#pragma unroll
    for (int off = 32; off > 0; off >>= 1) {
#pragma unroll
      for (int k = 0; k < 4; ++k) {
        s[k] += __shfl_xor(s[k], off);
        qq[k] += __shfl_xor(qq[k], off);
      }
    }
    if (lane == 0) {
#pragma unroll
      for (int k = 0; k < 4; ++k) {
        lds_st[wave][k] = s[k];
        lds_st[wave][4 + k] = qq[k];
      }
    }
    __syncthreads();
    if (tid < 8)
      P[(size_t)bid * 128 + tid] = lds_st[0][tid] + lds_st[1][tid] +
                                   lds_st[2][tid] + lds_st[3][tid];
  }
  grid.sync();
  // A-reduce (8 cols), every block
  {
    int col = tid & 7, grp = tid >> 3;  // 32 row-groups
    float s = 0.f;
    for (int r = grp; r < nblk; r += 32) s += P[(size_t)r * 128 + col];
    red_l[tid] = s;
    __syncthreads();
    if (tid < 8) {
      float t = 0.f;
#pragma unroll
      for (int g = 0; g < 32; ++g) t += red_l[g * 8 + tid];
      S_lds[tid] = t;
    }
    __syncthreads();
  }
  float sc0[4], sh0[4];
#pragma unroll
  for (int k = 0; k < 4; ++k) {
    float mean = S_lds[k] * INV_B;
    float var = fmaf(-mean, mean, S_lds[4 + k] * INV_B);
    float rs = rsqrtf(var + EPS);
    sc0[k] = bn0g[k] * rs;
    sh0[k] = fmaf(-sc0[k], mean, bn0b[k]);
  }
  float w0c[4];
#pragma unroll
  for (int k = 0; k < 4; ++k) w0c[k] = W0[k * 64 + lane];
  float b0c = b0[lane];

  //====== phase B: z1 stats (grid-stride chunks of 1024 rows) ======
  {
    float s = 0.f, qq = 0.f;
    for (int c = bid; c < 1024; c += nblk) {
      size_t r0 = (size_t)c * 1024 + (size_t)wave * 256;
      for (int r = 0; r < 256; ++r) {
        f4v xv = *(const f4v*)(x + (r0 + r) * 4);
        float acc = b0c;
#pragma unroll
        for (int k = 0; k < 4; ++k)
          acc = fmaf(fmaf(xv[k], sc0[k], sh0[k]), w0c[k], acc);
        float z = tanh_fast(acc);
        s += z;
        qq = fmaf(z, z, qq);
      }
    }
    __syncthreads();
    lds_st[wave][lane] = s;
    lds_st[wave][64 + lane] = qq;
    __syncthreads();
    if (tid < 128)
      P[(size_t)bid * 128 + tid] = lds_st[0][tid] + lds_st[1][tid] +
                                   lds_st[2][tid] + lds_st[3][tid];
  }
  grid_reduce128(P, P2, S_lds, red_l, bid, tid, nblk, grid);
  float mean1 = S_lds[lane] * INV_B;
  float var1 = fmaf(-mean1, mean1, S_lds[64 + lane] * INV_B);
  float A1c = gamma0[lane] * rsqrtf(var1 + EPS);
  float B1c = fmaf(-A1c, mean1, beta0[lane]);

  //====== phase C: k_first (grid-stride tiles) ======
  {
    float bbv[4];
    bfrag bwb[4][2];
#pragma unroll
    for (int nt = 0; nt < 4; ++nt) {
      bbv[nt] = bh[nt * 16 + l15];
#pragma unroll
      for (int kt = 0; kt < 2; ++kt)
        bwb[nt][kt] =
            *(const bfrag*)(WT + (nt * 16 + l15) * 64 + kt * 32 + q * 8);
    }
    float sAcc[4] = {0.f, 0.f, 0.f, 0.f}, qAcc[4] = {0.f, 0.f, 0.f, 0.f};
    for (int t = bid; t < NTILES; t += nblk) {
      const size_t r0 = (size_t)t * 128;
      if (lane < 32)
        *(f4v*)&lds_x[(wr + lane) * 4] =
            *(const f4v*)(x + (r0 + wr + lane) * 4);
      for (int e = 0; e < 32; ++e) {
        int row = wr + e;
        float acc = b0c;
#pragma unroll
        for (int k = 0; k < 4; ++k)
          acc = fmaf(fmaf(lds_x[row * 4 + k], sc0[k], sh0[k]), w0c[k], acc);
        float z = tanh_fast(acc);
        ly[row * 72 + lane] = f2bf(fmaf(A1c, z, B1c));
      }
      bfrag af[2][2];
#pragma unroll
      for (int mt = 0; mt < 2; ++mt)
#pragma unroll
        for (int kt = 0; kt < 2; ++kt) {
          af[mt][kt] =
              *(const bfrag*)&ly[(wr + mt * 16 + l15) * 72 + kt * 32 + q * 8];
          *(bfrag*)(Y + (r0 + wr + mt * 16 + l15) * 64 + kt * 32 + q * 8) =
              af[mt][kt];
        }
      facc acc2[2][4];
#pragma unroll
      for (int mt = 0; mt < 2; ++mt)
#pragma unroll
        for (int nt = 0; nt < 4; ++nt) {
          acc2[mt][nt][0] = bbv[nt]; acc2[mt][nt][1] = bbv[nt];
          acc2[mt][nt][2] = bbv[nt]; acc2[mt][nt][3] = bbv[nt];
        }
#pragma unroll
      for (int mt = 0; mt < 2; ++mt)
#pragma unroll
        for (int nt = 0; nt < 4; ++nt)
#pragma unroll
          for (int kt = 0; kt < 2; ++kt)
            acc2[mt][nt] = __builtin_amdgcn_mfma_f32_16x16x32_bf16(
                af[mt][kt], bwb[nt][kt], acc2[mt][nt], 0, 0, 0);
#pragma unroll
      for (int nt = 0; nt < 4; ++nt)
#pragma unroll
        for (int mt = 0; mt < 2; ++mt)
#pragma unroll
          for (int i = 0; i < 4; ++i) {
            float z = tanh_fast(acc2[mt][nt][i]);
            sAcc[nt] += z;
            qAcc[nt] = fmaf(z, z, qAcc[nt]);
          }
    }
    __syncthreads();
#pragma unroll
    for (int nt = 0; nt < 4; ++nt) {
      float s = sAcc[nt], ss = qAcc[nt];
      s += __shfl_xor(s, 16); s += __shfl_xor(s, 32);
      ss += __shfl_xor(ss, 16); ss += __shfl_xor(ss, 32);
      if (q == 0) {
        lds_st[wave][nt * 16 + l15] = s;
        lds_st[wave][64 + nt * 16 + l15] = ss;
      }
    }
    __syncthreads();
    if (tid < 128)
      P[(size_t)bid * 128 + tid] = lds_st[0][tid] + lds_st[1][tid] +
                                   lds_st[2][tid] + lds_st[3][tid];
  }
  grid_reduce128(P, P2, S_lds, red_l, bid, tid, nblk, grid);

  //====== phases D,E,F: k_mid x3 ======
  const bfrag bI0 = make_ident(l15, q, 0);
  const bfrag bI1 = make_ident(l15, q, 1);
  for (int layer = 0; layer < 3; ++layer) {
    float Av[4], Bv[4], bav[4], bbv[4];
#pragma unroll
    for (int nt = 0; nt < 4; ++nt) {
      int c = nt * 16 + l15;
      float mean = S_lds[c] * INV_B;
      float var = fmaf(-mean, mean, S_lds[64 + c] * INV_B);
      float A = gh[layer * 64 + c] * rsqrtf(var + EPS);
      Av[nt] = A;
      Bv[nt] = fmaf(-A, mean, beh[layer * 64 + c]);
      bav[nt] = bh[layer * 64 + c];
      bbv[nt] = bh[(layer + 1) * 64 + c];
    }
    bfrag bwa[4][2], bwb[4][2];
#pragma unroll
    for (int nt = 0; nt < 4; ++nt)
#pragma unroll
      for (int kt = 0; kt < 2; ++kt) {
        bwa[nt][kt] = *(const bfrag*)(WT + layer * 4096 +
                                      (nt * 16 + l15) * 64 + kt * 32 + q * 8);
        bwb[nt][kt] = *(const bfrag*)(WT + (layer + 1) * 4096 +
                                      (nt * 16 + l15) * 64 + kt * 32 + q * 8);
      }
    float sAcc[4] = {0.f, 0.f, 0.f, 0.f}, qAcc[4] = {0.f, 0.f, 0.f, 0.f};
    for (int t = bid; t < NTILES; t += nblk) {
      const size_t r0 = (size_t)t * 128;
      bfrag af[2][2];
#pragma unroll
      for (int mt = 0; mt < 2; ++mt)
#pragma unroll
        for (int kt = 0; kt < 2; ++kt)
          af[mt][kt] = *(const bfrag*)(Y + (r0 + wr + mt * 16 + l15) * 64 +
                                       kt * 32 + q * 8);
#pragma unroll
      for (int mt = 0; mt < 2; ++mt) {
        facc acc[4], yC[4];
#pragma unroll
        for (int nt = 0; nt < 4; ++nt) {
          acc[nt][0] = bav[nt]; acc[nt][1] = bav[nt];
          acc[nt][2] = bav[nt]; acc[nt][3] = bav[nt];
          yC[nt][0] = 0.f; yC[nt][1] = 0.f; yC[nt][2] = 0.f; yC[nt][3] = 0.f;
        }
#pragma unroll
        for (int nt = 0; nt < 4; ++nt) {
#pragma unroll
          for (int kt = 0; kt < 2; ++kt)
            acc[nt] = __builtin_amdgcn_mfma_f32_16x16x32_bf16(
                af[mt][kt], bwa[nt][kt], acc[nt], 0, 0, 0);
          yC[nt] = __builtin_amdgcn_mfma_f32_16x16x32_bf16(
              af[mt][nt >> 1], (nt & 1) ? bI1 : bI0, yC[nt], 0, 0, 0);
        }
#pragma unroll
        for (int nt = 0; nt < 4; ++nt) {
          int c = nt * 16 + l15;
          float A = Av[nt], Bc = Bv[nt];
#pragma unroll
          for (int i = 0; i < 4; ++i) {
            int rl = wr + mt * 16 + q * 4 + i;
            float z = tanh_fast(acc[nt][i]);
            ly[rl * 72 + c] = f2bf(fmaf(A, z, Bc) + yC[nt][i]);
          }
        }
      }
      bfrag af2[2][2];
#pragma unroll
      for (int mt = 0; mt < 2; ++mt)
#pragma unroll
        for (int kt = 0; kt < 2; ++kt) {
          af2[mt][kt] =
              *(const bfrag*)&ly[(wr + mt * 16 + l15) * 72 + kt * 32 + q * 8];
          *(bfrag*)(Y + (r0 + wr + mt * 16 + l15) * 64 + kt * 32 + q * 8) =
              af2[mt][kt];
        }
      facc acc2[2][4];
#pragma unroll
      for (int mt = 0; mt < 2; ++mt)
#pragma unroll
        for (int nt = 0; nt < 4; ++nt) {
          acc2[mt][nt][0] = bbv[nt]; acc2[mt][nt][1] = bbv[nt];
          acc2[mt][nt][2] = bbv[nt]; acc2[mt][nt][3] = bbv[nt];
        }
#pragma unroll
      for (int mt = 0; mt < 2; ++mt)
#pragma unroll
        for (int nt = 0; nt < 4; ++nt)
#pragma unroll
          for (int kt = 0; kt < 2; ++kt)
            acc2[mt][nt] = __builtin_amdgcn_mfma_f32_16x16x32_bf16(
                af2[mt][kt], bwb[nt][kt], acc2[mt][nt], 0, 0, 0);
#pragma unroll
      for (int nt = 0; nt < 4; ++nt)
#pragma unroll
        for (int mt = 0; mt < 2; ++mt)
#pragma unroll
          for (int i = 0; i < 4; ++i) {
            float z = tanh_fast(acc2[mt][nt][i]);
            sAcc[nt] += z;
            qAcc[nt] = fmaf(z, z, qAcc[nt]);
          }
    }
    __syncthreads();
#pragma unroll
    for (int nt = 0; nt < 4; ++nt) {
      float s = sAcc[nt], ss = qAcc[nt];
      s += __shfl_xor(s, 16); s += __shfl_xor(s, 32);
      ss += __shfl_xor(ss, 16); ss += __shfl_xor(ss, 32);
      if (q == 0) {
        lds_st[wave][nt * 16 + l15] = s;
        lds_st[wave][64 + nt * 16 + l15] = ss;
      }
    }
    __syncthreads();
    if (tid < 128)
      P[(size_t)bid * 128 + tid] = lds_st[0][tid] + lds_st[1][tid] +
                                   lds_st[2][tid] + lds_st[3][tid];
    grid_reduce128(P, P2, S_lds, red_l, bid, tid, nblk, grid);
  }

  //====== phase G: k_last (grid-stride tiles, register-only) ======
  {
    float Av[4], Bv[4], bav[4], wo[4][3];
#pragma unroll
    for (int nt = 0; nt < 4; ++nt) {
      int c = nt * 16 + l15;
      float mean = S_lds[c] * INV_B;
      float var = fmaf(-mean, mean, S_lds[64 + c] * INV_B);
      float A = gh[3 * 64 + c] * rsqrtf(var + EPS);
      Av[nt] = A;
      Bv[nt] = fmaf(-A, mean, beh[3 * 64 + c]);
      bav[nt] = bh[3 * 64 + c];
#pragma unroll
      for (int o = 0; o < 3; ++o) wo[nt][o] = Wout[c * 3 + o];
    }
    bfrag bwa[4][2];
#pragma unroll
    for (int nt = 0; nt < 4; ++nt)
#pragma unroll
      for (int kt = 0; kt < 2; ++kt)
        bwa[nt][kt] = *(const bfrag*)(WT + 3 * 4096 + (nt * 16 + l15) * 64 +
                                      kt * 32 + q * 8);
    float bo0 = bout[0], bo1 = bout[1], bo2 = bout[2];
    for (int t = bid; t < NTILES; t += nblk) {
      const size_t r0 = (size_t)t * 128;
      bfrag af[2][2];
#pragma unroll
      for (int mt = 0; mt < 2; ++mt)
#pragma unroll
        for (int kt = 0; kt < 2; ++kt)
          af[mt][kt] = *(const bfrag*)(Y + (r0 + wr + mt * 16 + l15) * 64 +
                                       kt * 32 + q * 8);
#pragma unroll
      for (int mt = 0; mt < 2; ++mt) {
        facc acc[4], yC[4];
#pragma unroll
        for (int nt = 0; nt < 4; ++nt) {
          acc[nt][0] = bav[nt]; acc[nt][1] = bav[nt];
          acc[nt][2] = bav[nt]; acc[nt][3] = bav[nt];
          yC[nt][0] = 0.f; yC[nt][1] = 0.f; yC[nt][2] = 0.f; yC[nt][3] = 0.f;
        }
#pragma unroll
        for (int nt = 0; nt < 4; ++nt) {
#pragma unroll
          for (int kt = 0; kt < 2; ++kt)
            acc[nt] = __builtin_amdgcn_mfma_f32_16x16x32_bf16(
                af[mt][kt], bwa[nt][kt], acc[nt], 0, 0, 0);
          yC[nt] = __builtin_amdgcn_mfma_f32_16x16x32_bf16(
              af[mt][nt >> 1], (nt & 1) ? bI1 : bI0, yC[nt], 0, 0, 0);
        }
#pragma unroll
        for (int i = 0; i < 4; ++i) {
          float o0 = 0.f, o1 = 0.f, o2 = 0.f;
#pragma unroll
          for (int nt = 0; nt < 4; ++nt) {
            float z = tanh_fast(acc[nt][i]);
            float yn = bf2f(f2bf(fmaf(Av[nt], z, Bv[nt]) + yC[nt][i]));
            o0 = fmaf(yn, wo[nt][0], o0);
            o1 = fmaf(yn, wo[nt][1], o1);
            o2 = fmaf(yn, wo[nt][2], o2);
          }
#pragma unroll
          for (int off = 1; off < 16; off <<= 1) {
            o0 += __shfl_xor(o0, off);
            o1 += __shfl_xor(o1, off);
            o2 += __shfl_xor(o2, off);
          }
          if (l15 == 0) {
            size_t ro = (r0 + wr + mt * 16 + q * 4 + i) * 3;
            out[ro] = o0 + bo0;
            out[ro + 1] = o1 + bo1;
            out[ro + 2] = o2 + bo2;
          }
        }
      }
    }
  }
}

// ===================== fallback multi-kernel path (R7, proven) ============

template <int W>
__global__ __launch_bounds__(256) void k_reduce(const float* __restrict__ P,
                                                float* __restrict__ S,
                                                int rows_per_blk) {
  __shared__ float red[256];
  const int tid = threadIdx.x;
  const int col = tid % W;
  const int grp = tid / W;
  const int G = 256 / W;
  size_t r0 = (size_t)blockIdx.x * rows_per_blk;
  float s = 0.f;
  for (int r = grp; r < rows_per_blk; r += G) s += P[(r0 + r) * W + col];
  red[tid] = s;
  __syncthreads();
  if (tid < W) {
    float t = 0.f;
#pragma unroll 4
    for (int g = 0; g < G; ++g) t += red[g * W + tid];
    atomicAdd(&S[tid], t);
  }
}

__global__ __launch_bounds__(256) void k_stats_x(const float* __restrict__ x,
                                                 float* __restrict__ P) {
  __shared__ float red[4][8];
  const int tid = threadIdx.x;
  const int wave = tid >> 6;
  size_t base = (size_t)blockIdx.x * 1024 + tid;
  float s[4] = {0.f, 0.f, 0.f, 0.f}, q[4] = {0.f, 0.f, 0.f, 0.f};
#pragma unroll
  for (int it = 0; it < 4; ++it) {
    f4v v = *(const f4v*)(x + (base + (size_t)it * 256) * 4);
#pragma unroll
    for (int k = 0; k < 4; ++k) { s[k] += v[k]; q[k] = fmaf(v[k], v[k], q[k]); }
  }
#pragma unroll
  for (int off = 32; off > 0; off >>= 1) {
#pragma unroll
    for (int k = 0; k < 4; ++k) {
      s[k] += __shfl_xor(s[k], off);
      q[k] += __shfl_xor(q[k], off);
    }
  }
  if ((tid & 63) == 0) {
#pragma unroll
    for (int k = 0; k < 4; ++k) { red[wave][k] = s[k]; red[wave][4 + k] = q[k]; }
  }
  __syncthreads();
  if (tid < 8)
    P[blockIdx.x * 8 + tid] =
        red[0][tid] + red[1][tid] + red[2][tid] + red[3][tid];
}

__global__ __launch_bounds__(256) void k_stats_z1(
    const float* __restrict__ x, const float* __restrict__ bn0g,
    const float* __restrict__ bn0b, const float* __restrict__ W0,
    const float* __restrict__ b0, const float* __restrict__ sx,
    float* __restrict__ P) {
  __shared__ float red[2][4][64];
  const int tid = threadIdx.x;
  const int lane = tid & 63;
  const int wave = tid >> 6;
  int gw = blockIdx.x * 4 + wave;
  float sc[4], sh[4];
#pragma unroll
  for (int k = 0; k < 4; ++k) {
    float mean = sx[k] * INV_B;
    float var = fmaf(-mean, mean, sx[4 + k] * INV_B);
    float rs = rsqrtf(var + EPS);
    sc[k] = bn0g[k] * rs;
    sh[k] = fmaf(-sc[k], mean, bn0b[k]);
  }
  float w[4];
#pragma unroll
  for (int k = 0; k < 4; ++k) w[k] = W0[k * 64 + lane];
  float bj = b0[lane];
  float s = 0.f, q = 0.f;
  size_t r0 = (size_t)gw * 256;
  for (int r = 0; r < 256; ++r) {
    f4v xv = *(const f4v*)(x + (r0 + r) * 4);
    float acc = bj;
#pragma unroll
    for (int k = 0; k < 4; ++k)
      acc = fmaf(fmaf(xv[k], sc[k], sh[k]), w[k], acc);
    float z = tanh_fast(acc);
    s += z;
    q = fmaf(z, z, q);
  }
  red[0][wave][lane] = s;
  red[1][wave][lane] = q;
  __syncthreads();
  if (tid < 128) {
    int which = tid >> 6, c = tid & 63;
    P[blockIdx.x * 128 + tid] = red[which][0][c] + red[which][1][c] +
                                red[which][2][c] + red[which][3][c];
  }
}

__global__ __launch_bounds__(256) void k_prep(const float* __restrict__ Wh,
                                              short* __restrict__ WT) {
  int idx = blockIdx.x * 256 + threadIdx.x;
  int l = idx >> 12, rem = idx & 4095, k = rem >> 6, c = rem & 63;
  WT[l * 4096 + c * 64 + k] = f2bf(Wh[l * 4096 + k * 64 + c]);
}

__global__ __launch_bounds__(256) void k_first(
    const float* __restrict__ x, const float* __restrict__ bn0g,
    const float* __restrict__ bn0b, const float* __restrict__ W0,
    const float* __restrict__ b0, const float* __restrict__ gamma0,
    const float* __restrict__ beta0, const float* __restrict__ sx,
    const float* __restrict__ s1, const short* __restrict__ WTb,
    const float* __restrict__ bb, float* __restrict__ P,
    short* __restrict__ Y) {
  __shared__ __align__(16) float lds_x[128 * 4];
  __shared__ __align__(16) short ly[128 * 72];
  __shared__ float lds_st[4][128];

  const int tid = threadIdx.x;
  const int lane = tid & 63;
  const int wave = tid >> 6;
  const int l15 = lane & 15;
  const int q = lane >> 4;
  const int wr = wave * 32;
  const size_t r0 = (size_t)blockIdx.x * 128;

  f4v xp;
  if (lane < 32) xp = *(const f4v*)(x + (r0 + wr + lane) * 4);

  float sc0[4], sh0[4];
#pragma unroll
  for (int k = 0; k < 4; ++k) {
    float mean = sx[k] * INV_B;
    float var = fmaf(-mean, mean, sx[4 + k] * INV_B);
    float rs = rsqrtf(var + EPS);
    sc0[k] = bn0g[k] * rs;
    sh0[k] = fmaf(-sc0[k], mean, bn0b[k]);
  }
  float w0c[4];
#pragma unroll
  for (int k = 0; k < 4; ++k) w0c[k] = W0[k * 64 + lane];
  float b0c = b0[lane];
  float mean1 = s1[lane] * INV_B;
  float var1 = fmaf(-mean1, mean1, s1[64 + lane] * INV_B);
  float A1c = gamma0[lane] * rsqrtf(var1 + EPS);
  float B1c = fmaf(-A1c, mean1, beta0[lane]);

  if (lane < 32) *(f4v*)&lds_x[(wr + lane) * 4] = xp;

  for (int e = 0; e < 32; ++e) {
    int row = wr + e;
    float acc = b0c;
#pragma unroll
    for (int k = 0; k < 4; ++k)
      acc = fmaf(fmaf(lds_x[row * 4 + k], sc0[k], sh0[k]), w0c[k], acc);
    float z = tanh_fast(acc);
    ly[row * 72 + lane] = f2bf(fmaf(A1c, z, B1c));
  }

  bfrag af[2][2];
#pragma unroll
  for (int mt = 0; mt < 2; ++mt)
#pragma unroll
    for (int kt = 0; kt < 2; ++kt) {
      af[mt][kt] =
          *(const bfrag*)&ly[(wr + mt * 16 + l15) * 72 + kt * 32 + q * 8];
      *(bfrag*)(Y + (r0 + wr + mt * 16 + l15) * 64 + kt * 32 + q * 8) =
          af[mt][kt];
    }
  float bbv[4];
  bfrag bwb[4][2];
#pragma unroll
  for (int nt = 0; nt < 4; ++nt) {
    bbv[nt] = bb[nt * 16 + l15];
#pragma unroll
    for (int kt = 0; kt < 2; ++kt)
      bwb[nt][kt] =
          *(const bfrag*)(WTb + (nt * 16 + l15) * 64 + kt * 32 + q * 8);
  }
  facc acc2[2][4];
#pragma unroll
  for (int mt = 0; mt < 2; ++mt)
#pragma unroll
    for (int nt = 0; nt < 4; ++nt) {
      acc2[mt][nt][0] = bbv[nt]; acc2[mt][nt][1] = bbv[nt];
      acc2[mt][nt][2] = bbv[nt]; acc2[mt][nt][3] = bbv[nt];
    }
#pragma unroll
  for (int mt = 0; mt < 2; ++mt)
#pragma unroll
    for (int nt = 0; nt < 4; ++nt)
#pragma unroll
      for (int kt = 0; kt < 2; ++kt)
        acc2[mt][nt] = __builtin_amdgcn_mfma_f32_16x16x32_bf16(
            af[mt][kt], bwb[nt][kt], acc2[mt][nt], 0, 0, 0);
#pragma unroll
  for (int nt = 0; nt < 4; ++nt) {
    float s = 0.f, ss = 0.f;
#pragma unroll
    for (int mt = 0; mt < 2; ++mt)
#pragma unroll
      for (int i = 0; i < 4; ++i) {
        float z = tanh_fast(acc2[mt][nt][i]);
        s += z;
        ss = fmaf(z, z, ss);
      }
    s += __shfl_xor(s, 16); s += __shfl_xor(s, 32);
    ss += __shfl_xor(ss, 16); ss += __shfl_xor(ss, 32);
    if (q == 0) {
      lds_st[wave][nt * 16 + l15] = s;
      lds_st[wave][64 + nt * 16 + l15] = ss;
    }
  }
  __syncthreads();
  if (tid < 128)
    P[(size_t)blockIdx.x * 128 + tid] =
        lds_st[0][tid] + lds_st[1][tid] + lds_st[2][tid] + lds_st[3][tid];
}

__global__ __launch_bounds__(256) void k_mid(
    short* __restrict__ Y, const short* __restrict__ WTa,
    const float* __restrict__ ba, const float* __restrict__ ga,
    const float* __restrict__ bea, const float* __restrict__ sa,
    const short* __restrict__ WTb, const float* __restrict__ bb,
    float* __restrict__ P) {
  __shared__ __align__(16) short ly[128 * 72];
  __shared__ float lds_st[4][128];

  const int tid = threadIdx.x;
  const int lane = tid & 63;
  const int wave = tid >> 6;
  const int l15 = lane & 15;
  const int q = lane >> 4;
  const int wr = wave * 32;
  const size_t r0 = (size_t)blockIdx.x * 128;

  bfrag af[2][2];
#pragma unroll
  for (int mt = 0; mt < 2; ++mt)
#pragma unroll
    for (int kt = 0; kt < 2; ++kt)
      af[mt][kt] =
          *(const bfrag*)(Y + (r0 + wr + mt * 16 + l15) * 64 + kt * 32 + q * 8);

  float Av[4], Bv[4], bav[4];
#pragma unroll
  for (int nt = 0; nt < 4; ++nt) {
    int c = nt * 16 + l15;
    float mean = sa[c] * INV_B;
    float var = fmaf(-mean, mean, sa[64 + c] * INV_B);
    float A = ga[c] * rsqrtf(var + EPS);
    Av[nt] = A;
    Bv[nt] = fmaf(-A, mean, bea[c]);
    bav[nt] = ba[c];
  }
  bfrag bwa[4][2];
#pragma unroll
  for (int nt = 0; nt < 4; ++nt)
#pragma unroll
    for (int kt = 0; kt < 2; ++kt)
      bwa[nt][kt] =
          *(const bfrag*)(WTa + (nt * 16 + l15) * 64 + kt * 32 + q * 8);
  const bfrag bI0 = make_ident(l15, q, 0);
  const bfrag bI1 = make_ident(l15, q, 1);

#pragma unroll
  for (int mt = 0; mt < 2; ++mt) {
    facc acc[4], yC[4];
#pragma unroll
    for (int nt = 0; nt < 4; ++nt) {
      acc[nt][0] = bav[nt]; acc[nt][1] = bav[nt];
      acc[nt][2] = bav[nt]; acc[nt][3] = bav[nt];
      yC[nt][0] = 0.f; yC[nt][1] = 0.f; yC[nt][2] = 0.f; yC[nt][3] = 0.f;
    }
#pragma unroll
    for (int nt = 0; nt < 4; ++nt) {
#pragma unroll
      for (int kt = 0; kt < 2; ++kt)
        acc[nt] = __builtin_amdgcn_mfma_f32_16x16x32_bf16(
            af[mt][kt], bwa[nt][kt], acc[nt], 0, 0, 0);
      yC[nt] = __builtin_amdgcn_mfma_f32_16x16x32_bf16(
          af[mt][nt >> 1], (nt & 1) ? bI1 : bI0, yC[nt], 0, 0, 0);
    }
#pragma unroll
    for (int nt = 0; nt < 4; ++nt) {
      int c = nt * 16 + l15;
      float A = Av[nt], Bc = Bv[nt];
#pragma unroll
      for (int i = 0; i < 4; ++i) {
        int rl = wr + mt * 16 + q * 4 + i;
        float z = tanh_fast(acc[nt][i]);
        ly[rl * 72 + c] = f2bf(fmaf(A, z, Bc) + yC[nt][i]);
      }
    }
  }

#pragma unroll
  for (int mt = 0; mt < 2; ++mt)
#pragma unroll
    for (int kt = 0; kt < 2; ++kt) {
      af[mt][kt] =
          *(const bfrag*)&ly[(wr + mt * 16 + l15) * 72 + kt * 32 + q * 8];
      *(bfrag*)(Y + (r0 + wr + mt * 16 + l15) * 64 + kt * 32 + q * 8) =
          af[mt][kt];
    }
  float bbv[4];
  bfrag bwb[4][2];
#pragma unroll
  for (int nt = 0; nt < 4; ++nt) {
    bbv[nt] = bb[nt * 16 + l15];
#pragma unroll
    for (int kt = 0; kt < 2; ++kt)
      bwb[nt][kt] =
          *(const bfrag*)(WTb + (nt * 16 + l15) * 64 + kt * 32 + q * 8);
  }
  facc acc2[2][4];
#pragma unroll
  for (int mt = 0; mt < 2; ++mt)
#pragma unroll
    for (int nt = 0; nt < 4; ++nt) {
      acc2[mt][nt][0] = bbv[nt]; acc2[mt][nt][1] = bbv[nt];
      acc2[mt][nt][2] = bbv[nt]; acc2[mt][nt][3] = bbv[nt];
    }
#pragma unroll
  for (int mt = 0; mt < 2; ++mt)
#pragma unroll
    for (int nt = 0; nt < 4; ++nt)
#pragma unroll
      for (int kt = 0; kt < 2; ++kt)
        acc2[mt][nt] = __builtin_amdgcn_mfma_f32_16x16x32_bf16(
            af[mt][kt], bwb[nt][kt], acc2[mt][nt], 0, 0, 0);
#pragma unroll
  for (int nt = 0; nt < 4; ++nt) {
    float s = 0.f, ss = 0.f;
#pragma unroll
    for (int mt = 0; mt < 2; ++mt)
#pragma unroll
      for (int i = 0; i < 4; ++i) {
        float z = tanh_fast(acc2[mt][nt][i]);
        s += z;
        ss = fmaf(z, z, ss);
      }
    s += __shfl_xor(s, 16); s += __shfl_xor(s, 32);
    ss += __shfl_xor(ss, 16); ss += __shfl_xor(ss, 32);
    if (q == 0) {
      lds_st[wave][nt * 16 + l15] = s;
      lds_st[wave][64 + nt * 16 + l15] = ss;
    }
  }
  __syncthreads();
  if (tid < 128)
    P[(size_t)blockIdx.x * 128 + tid] =
        lds_st[0][tid] + lds_st[1][tid] + lds_st[2][tid] + lds_st[3][tid];
}

__global__ __launch_bounds__(256) void k_last(
    const short* __restrict__ Y, const short* __restrict__ WTa,
    const float* __restrict__ ba, const float* __restrict__ ga,
    const float* __restrict__ bea, const float* __restrict__ sa,
    const float* __restrict__ Wout, const float* __restrict__ bout,
    float* __restrict__ out) {
  const int tid = threadIdx.x;
  const int lane = tid & 63;
  const int wave = tid >> 6;
  const int l15 = lane & 15;
  const int q = lane >> 4;
  const int wr = wave * 32;
  const size_t r0 = (size_t)blockIdx.x * 128;

  bfrag af[2][2];
#pragma unroll
  for (int mt = 0; mt < 2; ++mt)
#pragma unroll
    for (int kt = 0; kt < 2; ++kt)
      af[mt][kt] =
          *(const bfrag*)(Y + (r0 + wr + mt * 16 + l15) * 64 + kt * 32 + q * 8);

  float Av[4], Bv[4], bav[4], wo[4][3];
#pragma unroll
  for (int nt = 0; nt < 4; ++nt) {
    int c = nt * 16 + l15;
    float mean = sa[c] * INV_B;
    float var = fmaf(-mean, mean, sa[64 + c] * INV_B);
    float A = ga[c] * rsqrtf(var + EPS);
    Av[nt] = A;
    Bv[nt] = fmaf(-A, mean, bea[c]);
    bav[nt] = ba[c];
#pragma unroll
    for (int o = 0; o < 3; ++o) wo[nt][o] = Wout[c * 3 + o];
  }
  bfrag bwa[4][2];
#pragma unroll
  for (int nt = 0; nt < 4; ++nt)
#pragma unroll
    for (int kt = 0; kt < 2; ++kt)
      bwa[nt][kt] =
          *(const bfrag*)(WTa + (nt * 16 + l15) * 64 + kt * 32 + q * 8);
  const bfrag bI0 = make_ident(l15, q, 0);
  const bfrag bI1 = make_ident(l15, q, 1);
  float bo0 = bout[0], bo1 = bout[1], bo2 = bout[2];

#pragma unroll
  for (int mt = 0; mt < 2; ++mt) {
    facc acc[4], yC[4];
#pragma unroll
    for (int nt = 0; nt < 4; ++nt) {
      acc[nt][0] = bav[nt]; acc[nt][1] = bav[nt];
      acc[nt][2] = bav[nt]; acc[nt][3] = bav[nt];
      yC[nt][0] = 0.f; yC[nt][1] = 0.f; yC[nt][2] = 0.f; yC[nt][3] = 0.f;
    }
#pragma unroll
    for (int nt = 0; nt < 4; ++nt) {
#pragma unroll
      for (int kt = 0; kt < 2; ++kt)
        acc[nt] = __builtin_amdgcn_mfma_f32_16x16x32_bf16(
            af[mt][kt], bwa[nt][kt], acc[nt], 0, 0, 0);
      yC[nt] = __builtin_amdgcn_mfma_f32_16x16x32_bf16(
          af[mt][nt >> 1], (nt & 1) ? bI1 : bI0, yC[nt], 0, 0, 0);
    }
#pragma unroll
    for (int i = 0; i < 4; ++i) {
      float o0 = 0.f, o1 = 0.f, o2 = 0.f;
#pragma unroll
      for (int nt = 0; nt < 4; ++nt) {
        float z = tanh_fast(acc[nt][i]);
        float yn = bf2f(f2bf(fmaf(Av[nt], z, Bv[nt]) + yC[nt][i]));
        o0 = fmaf(yn, wo[nt][0], o0);
        o1 = fmaf(yn, wo[nt][1], o1);
        o2 = fmaf(yn, wo[nt][2], o2);
      }
#pragma unroll
      for (int off = 1; off < 16; off <<= 1) {
        o0 += __shfl_xor(o0, off);
        o1 += __shfl_xor(o1, off);
        o2 += __shfl_xor(o2, off);
      }
      if (l15 == 0) {
        size_t ro = (r0 + wr + mt * 16 + q * 4 + i) * 3;
        out[ro] = o0 + bo0;
        out[ro + 1] = o1 + bo1;
        out[ro + 2] = o2 + bo2;
      }
    }
  }
}

extern "C" void kernel_launch(void* const* d_in, const int* in_sizes, int n_in,
                              void* d_out, int out_size, void* d_ws,
                              size_t ws_size, hipStream_t stream) {
  (void)in_sizes; (void)n_in; (void)out_size; (void)ws_size;
  const float* x = (const float*)d_in[0];
  const float* bn0g = (const float*)d_in[1];
  const float* bn0b = (const float*)d_in[2];
  const float* W0 = (const float*)d_in[3];
  const float* b0 = (const float*)d_in[4];
  const float* gamma0 = (const float*)d_in[5];
  const float* beta0 = (const float*)d_in[6];
  const float* Wh = (const float*)d_in[7];
  const float* bh = (const float*)d_in[8];
  const float* gh = (const float*)d_in[9];
  const float* beh = (const float*)d_in[10];
  const float* Wout = (const float*)d_in[11];
  const float* bout = (const float*)d_in[12];
  float* out = (float*)d_out;

  char* ws = (char*)d_ws;
  short* Y = (short*)ws;                              // 128 MB
  const size_t YB = (size_t)NROWS * 64 * 2;
  short* WT = (short*)(ws + YB);                      // 32 KB
  float* P = (float*)(ws + YB + 32768);               // up to 1024x128 = 512 KB
  float* P2 = (float*)(ws + YB + 32768 + 524288);     // 128x128 = 64 KB
  // fallback-only region
  float* stats = (float*)(ws + YB + 32768 + 524288 + 65536);  // 648 floats
  float* Pmk = (float*)(ws + YB + 32768 + 524288 + 65536 + 4096);  // 4 MB

  // ---- try cooperative single-kernel ----
  int maxb = 0;
  hipError_t oe =
      hipOccupancyMaxActiveBlocksPerMultiprocessor(&maxb, k_net, 256, 0);
  int nblk = (oe == hipSuccess) ? maxb * 256 : 0;  // 256 CUs on MI355X
  if (nblk > 1024) nblk = 1024;
  nblk = (nblk / 128) * 128;

  hipError_t le = hipErrorUnknown;
  if (nblk >= 128) {
    void* args[] = {(void*)&x,      (void*)&bn0g, (void*)&bn0b, (void*)&W0,
                    (void*)&b0,     (void*)&gamma0, (void*)&beta0,
                    (void*)&Wh,     (void*)&bh,   (void*)&gh,   (void*)&beh,
                    (void*)&Wout,   (void*)&bout, (void*)&WT,   (void*)&P,
                    (void*)&P2,     (void*)&Y,    (void*)&out};
    le = hipLaunchCooperativeKernel((const void*)k_net, dim3(nblk), dim3(256),
                                    args, 0, stream);
  }
  if (le == hipSuccess) return;
  (void)hipGetLastError();  // clear sticky error from failed coop attempt

  // ---- fallback: proven multi-kernel path ----
  float* Sx = stats;
  float* S1 = stats + 8;
  float* S2 = stats + 136;
  float* S3 = stats + 264;
  float* S4 = stats + 392;
  float* S5 = stats + 520;

  hipMemsetAsync(stats, 0, 648 * sizeof(float), stream);
  k_prep<<<64, 256, 0, stream>>>(Wh, WT);
  k_stats_x<<<1024, 256, 0, stream>>>(x, Pmk);
  k_reduce<8><<<8, 256, 0, stream>>>(Pmk, Sx, 128);
  k_stats_z1<<<1024, 256, 0, stream>>>(x, bn0g, bn0b, W0, b0, Sx, Pmk);
  k_reduce<128><<<8, 256, 0, stream>>>(Pmk, S1, 128);
  k_first<<<8192, 256, 0, stream>>>(x, bn0g, bn0b, W0, b0, gamma0, beta0, Sx,
                                    S1, WT, bh, Pmk, Y);
  k_reduce<128><<<64, 256, 0, stream>>>(Pmk, S2, 128);
  k_mid<<<8192, 256, 0, stream>>>(Y, WT, bh, gh, beh, S2, WT + 4096, bh + 64,
                                  Pmk);
  k_reduce<128><<<64, 256, 0, stream>>>(Pmk, S3, 128);
  k_mid<<<8192, 256, 0, stream>>>(Y, WT + 4096, bh + 64, gh + 64, beh + 64, S3,
                                  WT + 2 * 4096, bh + 128, Pmk);
  k_reduce<128><<<64, 256, 0, stream>>>(Pmk, S4, 128);
  k_mid<<<8192, 256, 0, stream>>>(Y, WT + 2 * 4096, bh + 128, gh + 128,
                                  beh + 128, S4, WT + 3 * 4096, bh + 192, Pmk);
  k_reduce<128><<<64, 256, 0, stream>>>(Pmk, S5, 128);
  k_last<<<8192, 256, 0, stream>>>(Y, WT + 3 * 4096, bh + 192, gh + 192,
                                   beh + 192, S5, Wout, bout, out);
}